// Round 1
// 320.593 us; speedup vs baseline: 1.0261x; 1.0261x over previous
//
#include <hip/hip_runtime.h>
#include <math.h>

// B=64, M=128, J=512, T=513 (padded to TPAD=544), E=256, H=16, D=16; out (64, 65664) fp32.

#define LDT 68    // 64-row A-tile LDS leading dim (fp32 gemms)
#define LDB 132   // 128-col B-tile LDS leading dim (fp32 gemms)
#define TPAD 544  // 17 * 32; rows 513..543 are zero pads (exp(0)=1 -> subtract 31 from l)

typedef __attribute__((ext_vector_type(8))) short bf16x8;   // 8 bf16 = 4 VGPR
typedef __attribute__((ext_vector_type(4))) float f32x4;    // MFMA acc

static __device__ inline unsigned short f2bf(float x) {     // RNE fp32->bf16
  unsigned u = __float_as_uint(x);
  return (unsigned short)((u + 0x7fffu + ((u >> 16) & 1u)) >> 16);
}
static __device__ inline float bf2f(unsigned short h) {
  return __uint_as_float(((unsigned)h) << 16);
}
static __device__ inline unsigned pk(unsigned short a, unsigned short b) {
  return (unsigned)a | ((unsigned)b << 16);
}

// ---------------------------------------------------------------------------
// One-time W split+transpose: Wt[col][k] (bf16 hi/lo), col 0..255 = Wk cols,
// 256..511 = Wv cols. grid 512 blocks x 256 thr (thread = k).
// ---------------------------------------------------------------------------
__global__ void prep_wt(const float* __restrict__ Wk, const float* __restrict__ Wv,
                        unsigned short* __restrict__ Wth, unsigned short* __restrict__ Wtl)
{
  const int c = blockIdx.x, k = threadIdx.x;
  const float x = (c < 256) ? Wk[k * 256 + c] : Wv[k * 256 + (c - 256)];
  const unsigned short h = f2bf(x);
  Wth[c * 256 + k] = h;
  Wtl[c * 256 + k] = f2bf(x - bf2f(h));
}

// ---------------------------------------------------------------------------
// Split-bf16 MFMA GEMM: C(34816 x 512) = vjobs_padded(34816 x 256) @ [Wk|Wv].
// Rows are (b, t) with t in [0,544): t=0 skip token, 1..512 jobs, >=513 ZERO
// pad rows (so the MFMA attention kernel needs no tail handling).
// 128x128 tile, 256 thr = 4 waves (2x2, each 64x64 via 4x4 16x16x32 tiles).
// C = Ah*Bh + Ah*Bl + Al*Bh  (error ~2^-17, fp32-grade for this use).
// ---------------------------------------------------------------------------
__global__ __launch_bounds__(256) void gemm_kv_mfma(
    const float* __restrict__ jobs, const float* __restrict__ skip,
    const unsigned short* __restrict__ Wth, const unsigned short* __restrict__ Wtl,
    float* __restrict__ Kw, float* __restrict__ Vw)
{
  __shared__ short Ah[128 * 32], Al[128 * 32];   // [row][k] bf16, 8KB each
  __shared__ short Bh[128 * 32], Bl[128 * 32];   // [col][k] bf16
  const int tid = threadIdx.x;
  const int bx = blockIdx.x, by = blockIdx.y;

  const int r16 = tid >> 1;
  const int h16 = (tid & 1) << 4;
  const int rg = by * 128 + r16;                 // 0..34815 exact
  const int bb = rg / TPAD, tt = rg - bb * TPAD;
  const bool padr = (tt >= 513);
  const float* arow = (tt == 0 || padr) ? skip
                    : (jobs + ((size_t)(bb * 512 + tt - 1) << 8));
  const unsigned short* bhrow = Wth + ((size_t)(bx * 128 + r16) << 8);
  const unsigned short* blrow = Wtl + ((size_t)(bx * 128 + r16) << 8);

  const int w = tid >> 6, lane = tid & 63;
  const int wr = (w >> 1) << 6, wc = (w & 1) << 6;
  const int fm = lane & 15, fq = lane >> 4;

  f32x4 acc[4][4] = {};

  for (int kk = 0; kk < 256; kk += 32) {
    const float4 a0 = *(const float4*)(arow + kk + h16);
    const float4 a1 = *(const float4*)(arow + kk + h16 + 4);
    const float4 a2 = *(const float4*)(arow + kk + h16 + 8);
    const float4 a3 = *(const float4*)(arow + kk + h16 + 12);
    const int4 bh0 = *(const int4*)(bhrow + kk + h16);
    const int4 bh1 = *(const int4*)(bhrow + kk + h16 + 8);
    const int4 bl0 = *(const int4*)(blrow + kk + h16);
    const int4 bl1 = *(const int4*)(blrow + kk + h16 + 8);

    unsigned short h[16], l[16];
    const float av[16] = {a0.x,a0.y,a0.z,a0.w, a1.x,a1.y,a1.z,a1.w,
                          a2.x,a2.y,a2.z,a2.w, a3.x,a3.y,a3.z,a3.w};
    #pragma unroll
    for (int i = 0; i < 16; ++i) {
      const float x = padr ? 0.f : av[i];
      h[i] = f2bf(x);
      l[i] = f2bf(x - bf2f(h[i]));
    }

    __syncthreads();
    const int so = r16 * 32 + h16;
    ((int4*)&Ah[so])[0] = make_int4(pk(h[0],h[1]), pk(h[2],h[3]), pk(h[4],h[5]), pk(h[6],h[7]));
    ((int4*)&Ah[so])[1] = make_int4(pk(h[8],h[9]), pk(h[10],h[11]), pk(h[12],h[13]), pk(h[14],h[15]));
    ((int4*)&Al[so])[0] = make_int4(pk(l[0],l[1]), pk(l[2],l[3]), pk(l[4],l[5]), pk(l[6],l[7]));
    ((int4*)&Al[so])[1] = make_int4(pk(l[8],l[9]), pk(l[10],l[11]), pk(l[12],l[13]), pk(l[14],l[15]));
    *(int4*)&Bh[so] = bh0; *(int4*)&Bh[so + 8] = bh1;
    *(int4*)&Bl[so] = bl0; *(int4*)&Bl[so + 8] = bl1;
    __syncthreads();

    bf16x8 afh[4], afl[4], bfh[4], bfl[4];
    #pragma unroll
    for (int i = 0; i < 4; ++i) {
      const int ai = (wr + i * 16 + fm) * 32 + fq * 8;
      const int bi = (wc + i * 16 + fm) * 32 + fq * 8;
      afh[i] = *(const bf16x8*)&Ah[ai];
      afl[i] = *(const bf16x8*)&Al[ai];
      bfh[i] = *(const bf16x8*)&Bh[bi];
      bfl[i] = *(const bf16x8*)&Bl[bi];
    }
    #pragma unroll
    for (int mi = 0; mi < 4; ++mi)
      #pragma unroll
      for (int ni = 0; ni < 4; ++ni) {
        acc[mi][ni] = __builtin_amdgcn_mfma_f32_16x16x32_bf16(afh[mi], bfl[ni], acc[mi][ni], 0, 0, 0);
        acc[mi][ni] = __builtin_amdgcn_mfma_f32_16x16x32_bf16(afl[mi], bfh[ni], acc[mi][ni], 0, 0, 0);
        acc[mi][ni] = __builtin_amdgcn_mfma_f32_16x16x32_bf16(afh[mi], bfh[ni], acc[mi][ni], 0, 0, 0);
      }
  }

  float* Cb = (bx < 2) ? Kw : Vw;
  const int cb = ((bx & 1) << 7) + wc;
  #pragma unroll
  for (int mi = 0; mi < 4; ++mi) {
    #pragma unroll
    for (int r = 0; r < 4; ++r) {
      const int row = by * 128 + wr + mi * 16 + fq * 4 + r;
      float* crow = Cb + (size_t)row * 256 + cb;
      #pragma unroll
      for (int ni = 0; ni < 4; ++ni)
        crow[ni * 16 + fm] = acc[mi][ni][r];
    }
  }
}

// ---------------------------------------------------------------------------
// Wide tiled fp32 GEMM (Q and Wc projections): C[rows x 256] = A @ W (+bias)
// ---------------------------------------------------------------------------
template<int MODE>
__global__ __launch_bounds__(256) void gemm_wide(
    const float* __restrict__ A, const float* __restrict__ jobs,
    const float* __restrict__ skip, const float* __restrict__ W1,
    const float* __restrict__ bias, float* __restrict__ C1)
{
  __shared__ float As[16 * LDT];
  __shared__ float Bs[16 * LDB];
  const int tid = threadIdx.x;
  const int bx = blockIdx.x, by = blockIdx.y;

  const float* W = W1; float* C = C1; const int col0 = bx * 128;

  const int a_row = tid >> 2;
  const int a_k4  = (tid & 3) << 2;
  const int row = by * 64 + a_row;
  const float* arow;
  if (MODE == 0) {
    arow = A + ((size_t)row << 8);
  } else {
    const int bb = row / 513;
    const int t  = row - bb * 513;
    arow = (t == 0) ? skip : (jobs + ((size_t)(bb * 512 + t - 1) << 8));
  }

  const int b_k  = tid >> 4;
  const int b_c8 = (tid & 15) << 3;

  const int tr = tid >> 4, tc = tid & 15;
  float acc[4][8] = {};

  for (int k0 = 0; k0 < 256; k0 += 16) {
    const float4 av  = *(const float4*)(arow + k0 + a_k4);
    const float4 bv0 = *(const float4*)(W + ((size_t)(k0 + b_k) << 8) + col0 + b_c8);
    const float4 bv1 = *(const float4*)(W + ((size_t)(k0 + b_k) << 8) + col0 + b_c8 + 4);
    __syncthreads();
    As[(a_k4 + 0) * LDT + a_row] = av.x;
    As[(a_k4 + 1) * LDT + a_row] = av.y;
    As[(a_k4 + 2) * LDT + a_row] = av.z;
    As[(a_k4 + 3) * LDT + a_row] = av.w;
    *(float4*)&Bs[b_k * LDB + b_c8]     = bv0;
    *(float4*)&Bs[b_k * LDB + b_c8 + 4] = bv1;
    __syncthreads();
    #pragma unroll
    for (int k = 0; k < 16; ++k) {
      const float4 a  = *(const float4*)&As[k * LDT + (tr << 2)];
      const float4 b0 = *(const float4*)&Bs[k * LDB + (tc << 3)];
      const float4 b1 = *(const float4*)&Bs[k * LDB + (tc << 3) + 4];
      const float aa[4] = {a.x, a.y, a.z, a.w};
      #pragma unroll
      for (int i = 0; i < 4; ++i) {
        acc[i][0] = fmaf(aa[i], b0.x, acc[i][0]);
        acc[i][1] = fmaf(aa[i], b0.y, acc[i][1]);
        acc[i][2] = fmaf(aa[i], b0.z, acc[i][2]);
        acc[i][3] = fmaf(aa[i], b0.w, acc[i][3]);
        acc[i][4] = fmaf(aa[i], b1.x, acc[i][4]);
        acc[i][5] = fmaf(aa[i], b1.y, acc[i][5]);
        acc[i][6] = fmaf(aa[i], b1.z, acc[i][6]);
        acc[i][7] = fmaf(aa[i], b1.w, acc[i][7]);
      }
    }
  }

  const int oc = col0 + (tc << 3);
  float4 bsa = make_float4(0.f,0.f,0.f,0.f), bsb = make_float4(0.f,0.f,0.f,0.f);
  if (bias) { bsa = *(const float4*)(bias + oc); bsb = *(const float4*)(bias + oc + 4); }
  #pragma unroll
  for (int i = 0; i < 4; ++i) {
    float* crow = C + ((size_t)(by * 64 + (tr << 2) + i) << 8) + oc;
    float4 o0, o1;
    o0.x = acc[i][0]+bsa.x; o0.y = acc[i][1]+bsa.y; o0.z = acc[i][2]+bsa.z; o0.w = acc[i][3]+bsa.w;
    o1.x = acc[i][4]+bsb.x; o1.y = acc[i][5]+bsb.y; o1.z = acc[i][6]+bsb.z; o1.w = acc[i][7]+bsb.w;
    *(float4*)crow = o0; *(float4*)(crow + 4) = o1;
  }
}

// ---------------------------------------------------------------------------
// MFMA attention v7: one block per (h, b), 256 thr = 4 waves.
// Wave w: m-half = (w&2)*32, t-half = w&1 (t-steps of 32 rows over TPAD=544).
//
// S^T = K @ Q^T via 16x16x32 bf16 MFMA with the split packed into the
// K-dimension: A = [Kh | Kl] (d 0..15 in slots 0..15 hi, 16..31 lo),
// MFMA1 B = [Qh|Qh] -> KhQh + KlQh; MFMA2 B = [Ql|0] -> KhQl. 2 MFMAs = full
// 3-term split.
//
// A-tile rows are PERMUTED: abstract row i holds K row t0 + 8*(i>>2) + (i&3),
// so the C-frag (lane group g, reg r) = P[t0 + 8g + r][m]. With tileB at +4,
// lane-local P values are exactly the PV B-frag (kslot 8g+j <-> t0+8g+j):
// out^T = V^T @ P^T needs ZERO cross-lane data movement.
//
// Pads t=513..543 have K=V=0 -> S=0 -> exp=1 exactly: subtract 31 from l.
// Pair LDS reduce (t-halves) + shfl-xor group reduce, write normalized OC.
// ---------------------------------------------------------------------------
__global__ __launch_bounds__(256, 4) void attn_mfma(
    const float* __restrict__ Q, const float* __restrict__ K,
    const float* __restrict__ V, float* __restrict__ OC)
{
  const int h = blockIdx.x, b = blockIdx.y;
  const int tid = threadIdx.x;
  const int lane = tid & 63;
  const int w = __builtin_amdgcn_readfirstlane(tid >> 6);
  const int g = lane >> 4, fm = lane & 15;
  const int mh = (w & 2) << 5;              // 0 or 64
  const int th = w & 1;                     // t-half
  const int send = th ? 17 : 9;             // steps [0,9) | [9,17)
  int s = th ? 9 : 0;

  __shared__ float red[2 * 64 * 21];        // 10.5 KB, stride-21 (conflict-free)

  const int col = h * 16;
  const int dbase = (g & 1) << 3;           // d 0..7 | 8..15 per group parity

  // ---- Q B-frags (persistent): Bq1 = [Qh|Qh], Bq2 = [Ql|0] ----
  bf16x8 Bq1[4], Bq2[4];
  #pragma unroll
  for (int mt = 0; mt < 4; ++mt) {
    const float* qp = Q + ((size_t)(b * 128 + mh + mt * 16 + fm) << 8) + col + dbase;
    const float4 q0 = *(const float4*)qp;
    const float4 q1 = *(const float4*)(qp + 4);
    const float qv[8] = {q0.x,q0.y,q0.z,q0.w, q1.x,q1.y,q1.z,q1.w};
    #pragma unroll
    for (int j = 0; j < 8; ++j) {
      const float x = qv[j] * 0.25f;        // fold 1/sqrt(QKV)
      const unsigned short hh = f2bf(x);
      Bq1[mt][j] = (short)hh;
      Bq2[mt][j] = (short)((g < 2) ? f2bf(x - bf2f(hh)) : (unsigned short)0);
    }
  }

  f32x4 oT[4] = {};
  float lsum[4] = {0.f, 0.f, 0.f, 0.f};

  const float* Kb = K + (((size_t)b * TPAD) << 8) + col;
  const float* Vb = V + (((size_t)b * TPAD) << 8) + col;

  for (; s < send; ++s) {
    const int t0 = s << 5;

    // K A-frags, permuted rows: abstract row i -> t0 + 8*(i>>2) + (i&3); +4 for tileB
    bf16x8 KA, KB;
    {
      const int rA = t0 + ((fm & 12) << 1) + (fm & 3);
      const float* kp = Kb + ((size_t)rA << 8) + dbase;
      const float4 a0 = *(const float4*)kp;
      const float4 a1 = *(const float4*)(kp + 4);
      const float4 c0 = *(const float4*)(kp + 1024);   // +4 rows
      const float4 c1 = *(const float4*)(kp + 1028);
      const float ka[8] = {a0.x,a0.y,a0.z,a0.w, a1.x,a1.y,a1.z,a1.w};
      const float kc[8] = {c0.x,c0.y,c0.z,c0.w, c1.x,c1.y,c1.z,c1.w};
      #pragma unroll
      for (int j = 0; j < 8; ++j) {
        const unsigned short h0 = f2bf(ka[j]);
        const unsigned short h1 = f2bf(kc[j]);
        KA[j] = (short)((g < 2) ? h0 : f2bf(ka[j] - bf2f(h0)));
        KB[j] = (short)((g < 2) ? h1 : f2bf(kc[j] - bf2f(h1)));
      }
    }
    // V A-frags: row d = fm, kslot 8g+j -> V[t0+8g+j][col+fm]
    bf16x8 Vh, Vl;
    {
      const float* vp = Vb + (((size_t)(t0 + (g << 3))) << 8) + fm;
      #pragma unroll
      for (int j = 0; j < 8; ++j) {
        const float x = vp[(size_t)(j << 8)];
        const unsigned short hh = f2bf(x);
        Vh[j] = (short)hh;
        Vl[j] = (short)f2bf(x - bf2f(hh));
      }
    }

    #pragma unroll
    for (int mt = 0; mt < 4; ++mt) {
      f32x4 sA = {}, sB = {};
      sA = __builtin_amdgcn_mfma_f32_16x16x32_bf16(KA, Bq1[mt], sA, 0, 0, 0);
      sA = __builtin_amdgcn_mfma_f32_16x16x32_bf16(KA, Bq2[mt], sA, 0, 0, 0);
      sB = __builtin_amdgcn_mfma_f32_16x16x32_bf16(KB, Bq1[mt], sB, 0, 0, 0);
      sB = __builtin_amdgcn_mfma_f32_16x16x32_bf16(KB, Bq2[mt], sB, 0, 0, 0);
      // lane holds P[t0+8g+r][m] (tileA r=0..3) and P[t0+8g+4+r][m] (tileB)
      float p[8];
      p[0] = __expf(sA[0]); p[1] = __expf(sA[1]); p[2] = __expf(sA[2]); p[3] = __expf(sA[3]);
      p[4] = __expf(sB[0]); p[5] = __expf(sB[1]); p[6] = __expf(sB[2]); p[7] = __expf(sB[3]);
      lsum[mt] += ((p[0] + p[1]) + (p[2] + p[3])) + ((p[4] + p[5]) + (p[6] + p[7]));
      bf16x8 Ph, Pl;
      #pragma unroll
      for (int j = 0; j < 8; ++j) {
        const unsigned short hh = f2bf(p[j]);
        Ph[j] = (short)hh;
        Pl[j] = (short)f2bf(p[j] - bf2f(hh));
      }
      oT[mt] = __builtin_amdgcn_mfma_f32_16x16x32_bf16(Vh, Ph, oT[mt], 0, 0, 0);
      oT[mt] = __builtin_amdgcn_mfma_f32_16x16x32_bf16(Vh, Pl, oT[mt], 0, 0, 0);
      oT[mt] = __builtin_amdgcn_mfma_f32_16x16x32_bf16(Vl, Ph, oT[mt], 0, 0, 0);
    }
  }

  // ---- pair reduce (t-half 1 -> t-half 0), then normalize + write ----
  float* slot = red + ((w >> 1) * 1344);
  const int base = lane * 21;
  if (th) {
    #pragma unroll
    for (int mt = 0; mt < 4; ++mt) {
      slot[base + 4 * mt + 0] = oT[mt][0];
      slot[base + 4 * mt + 1] = oT[mt][1];
      slot[base + 4 * mt + 2] = oT[mt][2];
      slot[base + 4 * mt + 3] = oT[mt][3];
      slot[base + 16 + mt]    = lsum[mt];
    }
  }
  __syncthreads();
  if (!th) {
    #pragma unroll
    for (int mt = 0; mt < 4; ++mt) {
      oT[mt][0] += slot[base + 4 * mt + 0];
      oT[mt][1] += slot[base + 4 * mt + 1];
      oT[mt][2] += slot[base + 4 * mt + 2];
      oT[mt][3] += slot[base + 4 * mt + 3];
      float v = lsum[mt] + slot[base + 16 + mt];
      v += __shfl_xor(v, 16);
      v += __shfl_xor(v, 32);
      const float inv = 1.f / (v - 31.f);     // remove 31 pad rows (exp(0)=1)
      float4 o;
      o.x = oT[mt][0] * inv; o.y = oT[mt][1] * inv;
      o.z = oT[mt][2] * inv; o.w = oT[mt][3] * inv;
      // oT reg r = out[m][d = 4g + r]
      *(float4*)(OC + ((size_t)(b * 128 + mh + mt * 16 + fm) << 8) + col + (g << 2)) = o;
    }
  }
}

// ---------------------------------------------------------------------------
// Logits via split-bf16 MFMA (same validated skeleton as gemm_kv_mfma):
// C(128 x 513) per b = MH(128 x 256) @ vjobs(b)^T. A = MH rows, B = vjobs
// rows (row-major [t][k] IS the B [col][k] layout). Both split inline.
// Fused epilogue: e = exp(10*tanh(x/16)+mask-10), write out, deterministic
// per-block partial -> partials[b*5 + bx]. grid (5 t-tiles, 64 b).
// bx=4 covers only t=512 (write-guarded).
// ---------------------------------------------------------------------------
__global__ __launch_bounds__(256) void logits_mfma(
    const float* __restrict__ MH, const float* __restrict__ jobs,
    const float* __restrict__ skip, const float* __restrict__ mask,
    float* __restrict__ out, float* __restrict__ partials)
{
  __shared__ short Ah[128 * 32], Al[128 * 32];   // MH  [m][k] bf16 hi/lo
  __shared__ short Bh[128 * 32], Bl[128 * 32];   // jobs[t][k] bf16 hi/lo
  __shared__ float red[4];
  const int tid = threadIdx.x;
  const int bx = blockIdx.x;       // t-tile 0..4
  const int b  = blockIdx.y;

  const int r16 = tid >> 1;
  const int h16 = (tid & 1) << 4;
  const float* arow = MH + ((size_t)(b * 128 + r16) << 8);
  int tg = bx * 128 + r16; if (tg > 512) tg = 512;
  const float* brow = (tg == 0) ? skip : (jobs + ((size_t)(b * 512 + tg - 1) << 8));

  const int w = tid >> 6, lane = tid & 63;
  const int wr = (w >> 1) << 6, wc = (w & 1) << 6;
  const int fm = lane & 15, fq = lane >> 4;

  f32x4 acc[4][4] = {};

  for (int kk = 0; kk < 256; kk += 32) {
    const float4 a0 = *(const float4*)(arow + kk + h16);
    const float4 a1 = *(const float4*)(arow + kk + h16 + 4);
    const float4 a2 = *(const float4*)(arow + kk + h16 + 8);
    const float4 a3 = *(const float4*)(arow + kk + h16 + 12);
    const float4 b0 = *(const float4*)(brow + kk + h16);
    const float4 b1 = *(const float4*)(brow + kk + h16 + 4);
    const float4 b2 = *(const float4*)(brow + kk + h16 + 8);
    const float4 b3 = *(const float4*)(brow + kk + h16 + 12);

    unsigned short ha[16], la[16], hb[16], lb[16];
    const float av[16] = {a0.x,a0.y,a0.z,a0.w, a1.x,a1.y,a1.z,a1.w,
                          a2.x,a2.y,a2.z,a2.w, a3.x,a3.y,a3.z,a3.w};
    const float bv[16] = {b0.x,b0.y,b0.z,b0.w, b1.x,b1.y,b1.z,b1.w,
                          b2.x,b2.y,b2.z,b2.w, b3.x,b3.y,b3.z,b3.w};
    #pragma unroll
    for (int i = 0; i < 16; ++i) {
      ha[i] = f2bf(av[i]); la[i] = f2bf(av[i] - bf2f(ha[i]));
      hb[i] = f2bf(bv[i]); lb[i] = f2bf(bv[i] - bf2f(hb[i]));
    }

    __syncthreads();
    const int so = r16 * 32 + h16;
    ((int4*)&Ah[so])[0] = make_int4(pk(ha[0],ha[1]), pk(ha[2],ha[3]), pk(ha[4],ha[5]), pk(ha[6],ha[7]));
    ((int4*)&Ah[so])[1] = make_int4(pk(ha[8],ha[9]), pk(ha[10],ha[11]), pk(ha[12],ha[13]), pk(ha[14],ha[15]));
    ((int4*)&Al[so])[0] = make_int4(pk(la[0],la[1]), pk(la[2],la[3]), pk(la[4],la[5]), pk(la[6],la[7]));
    ((int4*)&Al[so])[1] = make_int4(pk(la[8],la[9]), pk(la[10],la[11]), pk(la[12],la[13]), pk(la[14],la[15]));
    ((int4*)&Bh[so])[0] = make_int4(pk(hb[0],hb[1]), pk(hb[2],hb[3]), pk(hb[4],hb[5]), pk(hb[6],hb[7]));
    ((int4*)&Bh[so])[1] = make_int4(pk(hb[8],hb[9]), pk(hb[10],hb[11]), pk(hb[12],hb[13]), pk(hb[14],hb[15]));
    ((int4*)&Bl[so])[0] = make_int4(pk(lb[0],lb[1]), pk(lb[2],lb[3]), pk(lb[4],lb[5]), pk(lb[6],lb[7]));
    ((int4*)&Bl[so])[1] = make_int4(pk(lb[8],lb[9]), pk(lb[10],lb[11]), pk(lb[12],lb[13]), pk(lb[14],lb[15]));
    __syncthreads();

    bf16x8 afh[4], afl[4], bfh[4], bfl[4];
    #pragma unroll
    for (int i = 0; i < 4; ++i) {
      const int ai = (wr + i * 16 + fm) * 32 + fq * 8;
      const int bi = (wc + i * 16 + fm) * 32 + fq * 8;
      afh[i] = *(const bf16x8*)&Ah[ai];
      afl[i] = *(const bf16x8*)&Al[ai];
      bfh[i] = *(const bf16x8*)&Bh[bi];
      bfl[i] = *(const bf16x8*)&Bl[bi];
    }
    #pragma unroll
    for (int mi = 0; mi < 4; ++mi)
      #pragma unroll
      for (int ni = 0; ni < 4; ++ni) {
        acc[mi][ni] = __builtin_amdgcn_mfma_f32_16x16x32_bf16(afh[mi], bfl[ni], acc[mi][ni], 0, 0, 0);
        acc[mi][ni] = __builtin_amdgcn_mfma_f32_16x16x32_bf16(afl[mi], bfh[ni], acc[mi][ni], 0, 0, 0);
        acc[mi][ni] = __builtin_amdgcn_mfma_f32_16x16x32_bf16(afh[mi], bfh[ni], acc[mi][ni], 0, 0, 0);
      }
  }

  // epilogue: lg = 10*tanh(acc/16) + mask; e = exp(lg-10); sum
  float lsum = 0.f;
  #pragma unroll
  for (int mi = 0; mi < 4; ++mi) {
    #pragma unroll
    for (int r = 0; r < 4; ++r) {
      const int m = wr + mi * 16 + fq * 4 + r;
      #pragma unroll
      for (int ni = 0; ni < 4; ++ni) {
        const int t = bx * 128 + wc + ni * 16 + fm;
        if (t < 513) {
          const float lg = 10.f * tanhf(acc[mi][ni][r] * 0.0625f)
                         + mask[((size_t)(b * 128 + m)) * 513 + t];
          const float e = __expf(lg - 10.f);
          out[(size_t)b * 65664 + (size_t)m * 513 + t] = e;
          lsum += e;
        }
      }
    }
  }
  #pragma unroll
  for (int off = 32; off; off >>= 1) lsum += __shfl_xor(lsum, off);
  if (lane == 0) red[w] = lsum;
  __syncthreads();
  if (tid == 0)
    partials[b * 5 + bx] = (red[0] + red[1]) + (red[2] + red[3]);
}

// Reduce 5 partials per batch -> 1/sum.
__global__ void sm_inv(const float* __restrict__ partials, float* __restrict__ invb)
{
  const int b = threadIdx.x;
  if (b < 64) {
    float s = 0.f;
    #pragma unroll
    for (int i = 0; i < 5; ++i) s += partials[b * 5 + i];
    invb[b] = 1.f / s;
  }
}

__global__ __launch_bounds__(256) void sm_norm(float* __restrict__ out,
                                               const float* __restrict__ invb)
{
  const int i4 = blockIdx.x * 256 + threadIdx.x;
  if (i4 < 1050624) {
    const int b = i4 / 16416;
    float4 v = ((float4*)out)[i4];
    const float s = invb[b];
    v.x *= s; v.y *= s; v.z *= s; v.w *= s;
    ((float4*)out)[i4] = v;
  }
}

// ---------------------------------------------------------------------------
extern "C" void kernel_launch(void* const* d_in, const int* in_sizes, int n_in,
                              void* d_out, int out_size, void* d_ws, size_t ws_size,
                              hipStream_t stream)
{
  const float* machine = (const float*)d_in[0];
  const float* jobs    = (const float*)d_in[1];
  const float* mask    = (const float*)d_in[2];
  const float* Wq      = (const float*)d_in[3];
  const float* Wk      = (const float*)d_in[4];
  const float* Wv      = (const float*)d_in[5];
  const float* Wc      = (const float*)d_in[6];
  const float* bc      = (const float*)d_in[7];
  const float* skip    = (const float*)d_in[8];

  // Workspace (floats). Peak 20,054,016 f ~ 80.2 MB.
  //   [0,        2097152)  Qw; overwritten in-place by attn_mfma as OC
  //   [2097152, 11010048)  Kw (64*544*256); ~400 f reused as partials/invb after attn
  //   [11010048,19922944)  Vw (64*544*256); first 2M reused as MH after attn
  //   [19922944,20054016)  Wth/Wtl (bf16) -> dead after kv gemm
  float* ws       = (float*)d_ws;
  float* Qw       = ws;
  float* Kw       = ws + 2097152;
  float* Vw       = ws + 11010048;
  unsigned short* Wth = (unsigned short*)(ws + 19922944);
  unsigned short* Wtl = Wth + 131072;
  float* MH       = ws + 11010048;     // overlays Vw (dead after attn)
  float* partials = ws + 2097152;      // overlays Kw (dead after attn)
  float* invb     = partials + 320;
  float* OC       = Qw;                // attn writes its own (h,b) slice only
  float* out      = (float*)d_out;

  // Q = machine @ Wq3 (fp32)
  gemm_wide<0><<<dim3(2, 128), 256, 0, stream>>>(
      machine, nullptr, nullptr, Wq, nullptr, Qw);
  // W split/transpose, then K|V = vjobs_padded @ [Wk|Wv] via split-bf16 MFMA
  prep_wt<<<512, 256, 0, stream>>>(Wk, Wv, Wth, Wtl);
  gemm_kv_mfma<<<dim3(4, 272), 256, 0, stream>>>(jobs, skip, Wth, Wtl, Kw, Vw);
  // MFMA attention: (h,b) blocks, 2x2 (m-half x t-half) waves, writes OC
  attn_mfma<<<dim3(16, 64), 256, 0, stream>>>(Qw, Kw, Vw, OC);
  // mh = out_concat @ Wc + bc (fp32)
  gemm_wide<0><<<dim3(2, 128), 256, 0, stream>>>(
      OC, nullptr, nullptr, Wc, bc, MH);
  // logits via split-bf16 MFMA + fused exp epilogue + partials
  logits_mfma<<<dim3(5, 64), 256, 0, stream>>>(MH, jobs, skip, mask, out, partials);
  sm_inv<<<1, 64, 0, stream>>>(partials, invb);
  sm_norm<<<4104, 256, 0, stream>>>(out, invb);
}